// Round 3
// baseline (372.585 us; speedup 1.0000x reference)
//
#include <hip/hip_runtime.h>
#include <stdint.h>

// Fused: LN -> QKV proj -> 8-head attention (flash) -> out proj -> LN
// x[4,64,256,512]; heads=8, dhead=64; GEMMs bf16 MFMA f32-accum, m97-style
// global_load_lds staged B with double-buffered LDS.

#define DIM   512
#define DHEAD 64
#define RLEN  256
#define TOK   65536
#define NALL  640   // q 512 | k 64 | v 64 columns, concatenated weights

typedef __bf16 bf16;
typedef __bf16 bf16x8 __attribute__((ext_vector_type(8)));
typedef float  f32x4  __attribute__((ext_vector_type(4)));

__device__ __forceinline__ f32x4 mfma16(bf16x8 a, bf16x8 b, f32x4 c) {
  return __builtin_amdgcn_mfma_f32_16x16x32_bf16(a, b, c, 0, 0, 0);
}
__device__ __forceinline__ f32x4 fzero4() {
  f32x4 z; z[0] = z[1] = z[2] = z[3] = 0.f; return z;
}
// async global->LDS, 16B per lane; LDS dest = wave-uniform base + lane*16,
// global source is per-lane.
__device__ __forceinline__ void gload_lds16(const void* g, void* l) {
  __builtin_amdgcn_global_load_lds(
      (const __attribute__((address_space(1))) void*)g,
      (__attribute__((address_space(3))) void*)l, 16, 0, 0);
}

// ---------------- K0: weights -> bf16, [n][k] layout ----------------
// wall[n][k], n<512 from W_q, n in [512,640) from W_kv. woutt[n][k].
__global__ __launch_bounds__(256) void k_prep(
    const float* __restrict__ Wq, const float* __restrict__ Wkv,
    const float* __restrict__ Wout,
    bf16* __restrict__ wall, bf16* __restrict__ woutt) {
  int t = blockIdx.x * 256 + threadIdx.x;   // grid covers 640*512
  int n = t >> 9, k = t & 511;
  float v = (n < DIM) ? Wq[k * DIM + n] : Wkv[k * 128 + (n - DIM)];
  wall[t] = (bf16)v;
  if (t < DIM * DIM) woutt[t] = (bf16)Wout[k * DIM + n];
}

// ---------------- K1: LN + Q/KV projection ----------------
// 64 token-rows per WG, 512 threads (8 waves x 80 cols). xn in swizzled LDS;
// B slabs [640][32k] double-buffered via global_load_lds (pre-swizzled src).
__global__ __launch_bounds__(512) void k_ln_qkv(
    const float* __restrict__ x, const float* __restrict__ gnorm,
    const bf16* __restrict__ wall,
    bf16* __restrict__ qbuf, bf16* __restrict__ kbuf, bf16* __restrict__ vbuf) {
  __shared__ bf16 xn[64][DIM];          // 64 KB, element-XOR ((r&7)<<3)
  __shared__ bf16 lb[2][NALL * 32];     // 2 x 40 KB, [n][32k], src-XOR'd
  const int t = threadIdx.x, wave = t >> 6, lane = t & 63;
  const int l15 = lane & 15, g = lane >> 4;
  const int row0 = blockIdx.x * 64;
  const int nsub = wave * 16 + (lane >> 2);
  const int kbl  = (lane & 3) * 16;

  // prologue: stage B slab for kk=0 (flies under the LN loads)
  #pragma unroll
  for (int c = 0; c < 5; ++c) {
    int n = c * 128 + nsub;
    int kb = kbl ^ ((n & 3) << 4);
    gload_lds16((const char*)(wall + (size_t)n * DIM) + kb,
                (char*)&lb[0][0] + c * 8192 + wave * 1024);
  }

  { // ---- LayerNorm: 8 threads per row ----
    const int r = t >> 3, sub = t & 7;
    const float* xp = x + (size_t)(row0 + r) * DIM + sub * 64;
    float4 buf[16];
    float s = 0.f, sq = 0.f;
    #pragma unroll
    for (int i = 0; i < 16; ++i) {
      buf[i] = ((const float4*)xp)[i];
      s  += buf[i].x + buf[i].y + buf[i].z + buf[i].w;
      sq += buf[i].x*buf[i].x + buf[i].y*buf[i].y + buf[i].z*buf[i].z + buf[i].w*buf[i].w;
    }
    s += __shfl_xor(s, 1); sq += __shfl_xor(sq, 1);
    s += __shfl_xor(s, 2); sq += __shfl_xor(sq, 2);
    s += __shfl_xor(s, 4); sq += __shfl_xor(sq, 4);
    float mean = s * (1.f / 512.f);
    float var  = sq * (1.f / 512.f) - mean * mean;
    float rs   = rsqrtf(var + 1e-5f);
    const float* gp = gnorm + sub * 64;
    #pragma unroll
    for (int i = 0; i < 16; i += 2) {
      bf16x8 v8;
      #pragma unroll
      for (int u = 0; u < 2; ++u) {
        float4 bv = buf[i + u];
        v8[u*4+0] = (bf16)((bv.x - mean) * rs * gp[(i+u)*4+0]);
        v8[u*4+1] = (bf16)((bv.y - mean) * rs * gp[(i+u)*4+1]);
        v8[u*4+2] = (bf16)((bv.z - mean) * rs * gp[(i+u)*4+2]);
        v8[u*4+3] = (bf16)((bv.w - mean) * rs * gp[(i+u)*4+3]);
      }
      int c = sub * 64 + i * 4;
      *(bf16x8*)&xn[r][c ^ ((r & 7) << 3)] = v8;
    }
  }
  __syncthreads();  // drains vmcnt: lb[0] ready; xn ready

  f32x4 acc[4][5];
  #pragma unroll
  for (int mi = 0; mi < 4; ++mi)
    #pragma unroll
    for (int ni = 0; ni < 5; ++ni) acc[mi][ni] = fzero4();
  const int w80 = wave * 80;

  #pragma unroll 2
  for (int step = 0; step < 16; ++step) {
    const int cur = step & 1;
    if (step < 15) {  // stage next slab into other buffer
      int kk = (step + 1) * 32;
      #pragma unroll
      for (int c = 0; c < 5; ++c) {
        int n = c * 128 + nsub;
        int kb = kbl ^ ((n & 3) << 4);
        gload_lds16((const char*)(wall + (size_t)n * DIM + kk) + kb,
                    (char*)&lb[cur ^ 1][0] + c * 8192 + wave * 1024);
      }
    }
    const int kk = step * 32;
    bf16x8 a[4], b[5];
    #pragma unroll
    for (int mi = 0; mi < 4; ++mi) {
      int rr = mi * 16 + l15;
      a[mi] = *(const bf16x8*)&xn[rr][(kk + g * 8) ^ ((rr & 7) << 3)];
    }
    #pragma unroll
    for (int ni = 0; ni < 5; ++ni) {
      int n = w80 + ni * 16 + l15;
      int kb = (g * 16) ^ ((n & 3) << 4);
      b[ni] = *(const bf16x8*)((const char*)&lb[cur][0] + n * 64 + kb);
    }
    #pragma unroll
    for (int mi = 0; mi < 4; ++mi)
      #pragma unroll
      for (int ni = 0; ni < 5; ++ni)
        acc[mi][ni] = mfma16(a[mi], b[ni], acc[mi][ni]);
    __syncthreads();  // next slab landed; everyone done with lb[cur]
  }

  // epilogue: cols [w80, w80+80) -> q / k / v
  #pragma unroll
  for (int ni = 0; ni < 5; ++ni) {
    int col0 = w80 + ni * 16;
    bf16* dst; int cstride;
    if (col0 < 512)      { dst = qbuf + (size_t)row0 * DIM   + col0        + l15; cstride = DIM; }
    else if (col0 < 576) { dst = kbuf + (size_t)row0 * DHEAD + (col0-512) + l15; cstride = DHEAD; }
    else                 { dst = vbuf + (size_t)row0 * DHEAD + (col0-576) + l15; cstride = DHEAD; }
    #pragma unroll
    for (int mi = 0; mi < 4; ++mi)
      #pragma unroll
      for (int jj = 0; jj < 4; ++jj)
        dst[(size_t)(mi * 16 + g * 4 + jj) * cstride] = (bf16)acc[mi][ni][jj];
  }
}

// ---------------- K2: flash attention per (b*n, head) ----------------
// 512 threads (8 waves x 32 q-rows). Q in regs; K, V^T chunk-staged in LDS.
// All LDS tiles XOR-swizzled: col ^ ((row&7)<<3).
__global__ __launch_bounds__(512) void k_attn(
    bf16* __restrict__ qbuf, const bf16* __restrict__ kbuf,
    const bf16* __restrict__ vbuf) {
  __shared__ bf16 lk[64][64];       // K chunk  [kvrow][d]
  __shared__ bf16 lvt[64][64];      // V^T chunk [d][kvrow]
  __shared__ bf16 lp[8][32][64];    // per-wave P tile [qrow][kvcol]
  const int t = threadIdx.x, wave = t >> 6, lane = t & 63;
  const int l15 = lane & 15, g = lane >> 4;
  const int bn = blockIdx.x >> 3, h = blockIdx.x & 7;
  const size_t tok0 = (size_t)bn * RLEN;
  const int m0 = wave * 32;

  bf16x8 aq[2][2];
  {
    const bf16* qb = qbuf + (tok0 + m0 + l15) * DIM + h * DHEAD + g * 8;
    #pragma unroll
    for (int mi = 0; mi < 2; ++mi)
      #pragma unroll
      for (int ks = 0; ks < 2; ++ks)
        aq[mi][ks] = *(const bf16x8*)(qb + (size_t)mi * 16 * DIM + ks * 32);
  }
  f32x4 o[2][4];
  float mrow[2][4], lrow[2][4];
  #pragma unroll
  for (int mi = 0; mi < 2; ++mi) {
    #pragma unroll
    for (int di = 0; di < 4; ++di) o[mi][di] = fzero4();
    #pragma unroll
    for (int jj = 0; jj < 4; ++jj) { mrow[mi][jj] = -1e30f; lrow[mi][jj] = 0.f; }
  }

  for (int j = 0; j < 4; ++j) {
    __syncthreads();
    { // stage K chunk (coalesced 16B) and V^T chunk
      const bf16* kc = kbuf + (tok0 + j * 64) * DHEAD;
      int r = t >> 3, c8 = (t & 7) * 8;
      *(bf16x8*)&lk[r][c8 ^ ((r & 7) << 3)] = *(const bf16x8*)(kc + r * DHEAD + c8);
      const bf16* vc = vbuf + (tok0 + j * 64) * DHEAD;
      int c = t & 63;
      #pragma unroll
      for (int i = 0; i < 8; ++i) {
        int rr = (t >> 6) + i * 8;
        lvt[c][rr ^ ((c & 7) << 3)] = vc[rr * DHEAD + c];
      }
    }
    __syncthreads();

    // S = Q K^T for this chunk
    f32x4 s[2][4];
    #pragma unroll
    for (int mi = 0; mi < 2; ++mi)
      #pragma unroll
      for (int nj = 0; nj < 4; ++nj) s[mi][nj] = fzero4();
    #pragma unroll
    for (int ks = 0; ks < 2; ++ks) {
      bf16x8 bk[4];
      #pragma unroll
      for (int nj = 0; nj < 4; ++nj)
        bk[nj] = *(const bf16x8*)&lk[nj * 16 + l15][(ks * 32 + g * 8) ^ ((l15 & 7) << 3)];
      #pragma unroll
      for (int mi = 0; mi < 2; ++mi)
        #pragma unroll
        for (int nj = 0; nj < 4; ++nj)
          s[mi][nj] = mfma16(aq[mi][ks], bk[nj], s[mi][nj]);
    }

    // online softmax update (scale = 1/8 folds SCALE*PB_ALPHA)
    #pragma unroll
    for (int mi = 0; mi < 2; ++mi) {
      #pragma unroll
      for (int jj = 0; jj < 4; ++jj) {
        float s0 = s[mi][0][jj] * 0.125f;
        float s1 = s[mi][1][jj] * 0.125f;
        float s2 = s[mi][2][jj] * 0.125f;
        float s3 = s[mi][3][jj] * 0.125f;
        float cm = fmaxf(fmaxf(s0, s1), fmaxf(s2, s3));
        cm = fmaxf(cm, __shfl_xor(cm, 1));
        cm = fmaxf(cm, __shfl_xor(cm, 2));
        cm = fmaxf(cm, __shfl_xor(cm, 4));
        cm = fmaxf(cm, __shfl_xor(cm, 8));
        float mold = mrow[mi][jj];
        float mnew = fmaxf(mold, cm);
        float alpha = __expf(mold - mnew);
        mrow[mi][jj] = mnew;
        float p0 = __expf(s0 - mnew), p1 = __expf(s1 - mnew);
        float p2 = __expf(s2 - mnew), p3 = __expf(s3 - mnew);
        float ps = p0 + p1 + p2 + p3;
        ps += __shfl_xor(ps, 1); ps += __shfl_xor(ps, 2);
        ps += __shfl_xor(ps, 4); ps += __shfl_xor(ps, 8);
        lrow[mi][jj] = lrow[mi][jj] * alpha + ps;
        #pragma unroll
        for (int di = 0; di < 4; ++di) o[mi][di][jj] *= alpha;
        int prow = mi * 16 + g * 4 + jj;
        int sw = (prow & 7) << 3;
        lp[wave][prow][( 0 + l15) ^ sw] = (bf16)p0;
        lp[wave][prow][(16 + l15) ^ sw] = (bf16)p1;
        lp[wave][prow][(32 + l15) ^ sw] = (bf16)p2;
        lp[wave][prow][(48 + l15) ^ sw] = (bf16)p3;
      }
    }
    __syncthreads();

    // O += P V
    #pragma unroll
    for (int ks = 0; ks < 2; ++ks) {
      bf16x8 pa[2], bv[4];
      #pragma unroll
      for (int mi = 0; mi < 2; ++mi)
        pa[mi] = *(const bf16x8*)&lp[wave][mi * 16 + l15][(ks * 32 + g * 8) ^ ((l15 & 7) << 3)];
      #pragma unroll
      for (int di = 0; di < 4; ++di)
        bv[di] = *(const bf16x8*)&lvt[di * 16 + l15][(ks * 32 + g * 8) ^ ((l15 & 7) << 3)];
      #pragma unroll
      for (int mi = 0; mi < 2; ++mi)
        #pragma unroll
        for (int di = 0; di < 4; ++di)
          o[mi][di] = mfma16(pa[mi], bv[di], o[mi][di]);
    }
  }

  // epilogue: normalize, write back in place
  #pragma unroll
  for (int mi = 0; mi < 2; ++mi)
    #pragma unroll
    for (int jj = 0; jj < 4; ++jj) {
      float inv = 1.0f / lrow[mi][jj];
      size_t row = tok0 + m0 + mi * 16 + g * 4 + jj;
      #pragma unroll
      for (int di = 0; di < 4; ++di)
        qbuf[row * DIM + h * DHEAD + di * 16 + l15] = (bf16)(o[mi][di][jj] * inv);
    }
}

// ---------------- K3: out projection + LN ----------------
// 64 rows/WG, 512 threads (8 waves x 64 cols). A staged once via
// global_load_lds (pre-swizzled src); B double-buffered like K1.
__global__ __launch_bounds__(512) void k_out_ln(
    const bf16* __restrict__ abuf, const bf16* __restrict__ woutt,
    const float* __restrict__ gout, float* __restrict__ out) {
  __shared__ bf16 la[64][DIM];        // 64 KB, element-XOR ((r&7)<<3)
  __shared__ bf16 lb[2][DIM * 32];    // 2 x 32 KB
  __shared__ float2 part[64][8];
  __shared__ float2 stats[64];
  const int t = threadIdx.x, wave = t >> 6, lane = t & 63;
  const int l15 = lane & 15, g = lane >> 4;
  const size_t row0 = (size_t)blockIdx.x * 64;
  const int nsub = wave * 16 + (lane >> 2);
  const int kbl  = (lane & 3) * 16;

  // stage B slab kk=0
  #pragma unroll
  for (int c = 0; c < 4; ++c) {
    int n = c * 128 + nsub;
    int kb = kbl ^ ((n & 3) << 4);
    gload_lds16((const char*)(woutt + (size_t)n * DIM) + kb,
                (char*)&lb[0][0] + c * 8192 + wave * 1024);
  }
  // stage A tile: r = c*8+wave, LDS(r, lane*16) <- G(r, lane*16 ^ (wave<<4))
  {
    const char* ab = (const char*)(abuf + row0 * DIM);
    int cb = (lane * 16) ^ (wave << 4);
    #pragma unroll
    for (int c = 0; c < 8; ++c) {
      int r = c * 8 + wave;
      gload_lds16(ab + (size_t)r * 1024 + cb,
                  (char*)&la[0][0] + c * 8192 + wave * 1024);
    }
  }
  __syncthreads();

  f32x4 acc[4][4];
  #pragma unroll
  for (int mi = 0; mi < 4; ++mi)
    #pragma unroll
    for (int ni = 0; ni < 4; ++ni) acc[mi][ni] = fzero4();
  const int n0 = wave * 64;

  #pragma unroll 2
  for (int step = 0; step < 16; ++step) {
    const int cur = step & 1;
    if (step < 15) {
      int kk = (step + 1) * 32;
      #pragma unroll
      for (int c = 0; c < 4; ++c) {
        int n = c * 128 + nsub;
        int kb = kbl ^ ((n & 3) << 4);
        gload_lds16((const char*)(woutt + (size_t)n * DIM + kk) + kb,
                    (char*)&lb[cur ^ 1][0] + c * 8192 + wave * 1024);
      }
    }
    const int kk = step * 32;
    bf16x8 a[4], b[4];
    #pragma unroll
    for (int mi = 0; mi < 4; ++mi) {
      int rr = mi * 16 + l15;
      a[mi] = *(const bf16x8*)&la[rr][(kk + g * 8) ^ ((rr & 7) << 3)];
    }
    #pragma unroll
    for (int ni = 0; ni < 4; ++ni) {
      int n = n0 + ni * 16 + l15;
      int kb = (g * 16) ^ ((n & 3) << 4);
      b[ni] = *(const bf16x8*)((const char*)&lb[cur][0] + n * 64 + kb);
    }
    #pragma unroll
    for (int mi = 0; mi < 4; ++mi)
      #pragma unroll
      for (int ni = 0; ni < 4; ++ni)
        acc[mi][ni] = mfma16(a[mi], b[ni], acc[mi][ni]);
    __syncthreads();
  }

  // LN partials: reduce over this wave's 64 cols, then across waves via LDS
  #pragma unroll
  for (int mi = 0; mi < 4; ++mi)
    #pragma unroll
    for (int jj = 0; jj < 4; ++jj) {
      float s = acc[mi][0][jj] + acc[mi][1][jj] + acc[mi][2][jj] + acc[mi][3][jj];
      float q = acc[mi][0][jj]*acc[mi][0][jj] + acc[mi][1][jj]*acc[mi][1][jj]
              + acc[mi][2][jj]*acc[mi][2][jj] + acc[mi][3][jj]*acc[mi][3][jj];
      s += __shfl_xor(s, 1); q += __shfl_xor(q, 1);
      s += __shfl_xor(s, 2); q += __shfl_xor(q, 2);
      s += __shfl_xor(s, 4); q += __shfl_xor(q, 4);
      s += __shfl_xor(s, 8); q += __shfl_xor(q, 8);
      if (l15 == 0) part[mi * 16 + g * 4 + jj][wave] = make_float2(s, q);
    }
  __syncthreads();
  if (t < 64) {
    float S = 0.f, Q = 0.f;
    #pragma unroll
    for (int w = 0; w < 8; ++w) { S += part[t][w].x; Q += part[t][w].y; }
    float mean = S * (1.f / 512.f);
    float var  = Q * (1.f / 512.f) - mean * mean;
    stats[t] = make_float2(mean, rsqrtf(var + 1e-5f));
  }
  __syncthreads();

  #pragma unroll
  for (int mi = 0; mi < 4; ++mi)
    #pragma unroll
    for (int ni = 0; ni < 4; ++ni) {
      int col = n0 + ni * 16 + l15;
      float gg = gout[col];
      #pragma unroll
      for (int jj = 0; jj < 4; ++jj) {
        int row = mi * 16 + g * 4 + jj;
        float2 st = stats[row];
        out[(row0 + row) * DIM + col] = (acc[mi][ni][jj] - st.x) * st.y * gg;
      }
    }
}

// ---------------- launch ----------------
extern "C" void kernel_launch(void* const* d_in, const int* in_sizes, int n_in,
                              void* d_out, int out_size, void* d_ws, size_t ws_size,
                              hipStream_t stream) {
  const float* x     = (const float*)d_in[0];
  const float* gnorm = (const float*)d_in[1];
  const float* Wq    = (const float*)d_in[2];
  const float* Wkv   = (const float*)d_in[3];
  const float* Wout  = (const float*)d_in[4];
  const float* gout  = (const float*)d_in[5];
  float* out = (float*)d_out;
  char* ws = (char*)d_ws;
  // ws layout (bytes): wall 640K | woutt 512K | qbuf 64M | kbuf 8M | vbuf 8M
  bf16* wall  = (bf16*)(ws);
  bf16* woutt = (bf16*)(ws + 655360);
  bf16* qbuf  = (bf16*)(ws + 1179648);
  bf16* kbuf  = (bf16*)((char*)qbuf + (size_t)TOK * DIM * 2);
  bf16* vbuf  = (bf16*)((char*)kbuf + (size_t)TOK * DHEAD * 2);

  k_prep  <<<dim3(1280), dim3(256), 0, stream>>>(Wq, Wkv, Wout, wall, woutt);
  k_ln_qkv<<<dim3(1024), dim3(512), 0, stream>>>(x, gnorm, wall, qbuf, kbuf, vbuf);
  k_attn  <<<dim3(2048), dim3(512), 0, stream>>>(qbuf, kbuf, vbuf);
  k_out_ln<<<dim3(1024), dim3(512), 0, stream>>>(qbuf, woutt, gout, out);
}

// Round 4
// 323.199 us; speedup vs baseline: 1.1528x; 1.1528x over previous
//
#include <hip/hip_runtime.h>
#include <stdint.h>

// Pipeline: kx_ln (LN->bf16) | k_gemm_qkv (m97 128x128) | k_attn (flash)
//           | k_gemm_out (m97) | k_ln_out (LN->f32)
// x[4,64,256,512]; heads=8, dhead=64.

#define DIM   512
#define DHEAD 64
#define RLEN  256
#define TOK   65536
#define NALL  640

typedef __bf16 bf16;
typedef __bf16 bf16x8 __attribute__((ext_vector_type(8)));
typedef float  f32x4  __attribute__((ext_vector_type(4)));

__device__ __forceinline__ f32x4 mfma16(bf16x8 a, bf16x8 b, f32x4 c) {
  return __builtin_amdgcn_mfma_f32_16x16x32_bf16(a, b, c, 0, 0, 0);
}
__device__ __forceinline__ f32x4 fzero4() {
  f32x4 z; z[0] = z[1] = z[2] = z[3] = 0.f; return z;
}
__device__ __forceinline__ void gload_lds16(const void* g, void* l) {
  __builtin_amdgcn_global_load_lds(
      (const __attribute__((address_space(1))) void*)g,
      (__attribute__((address_space(3))) void*)l, 16, 0, 0);
}

// ---------------- K0: weights -> bf16, [n][k] layout ----------------
__global__ __launch_bounds__(256) void k_prep(
    const float* __restrict__ Wq, const float* __restrict__ Wkv,
    const float* __restrict__ Wout,
    bf16* __restrict__ wall, bf16* __restrict__ woutt) {
  int t = blockIdx.x * 256 + threadIdx.x;   // grid covers 640*512
  int n = t >> 9, k = t & 511;
  float v = (n < DIM) ? Wq[k * DIM + n] : Wkv[k * 128 + (n - DIM)];
  wall[t] = (bf16)v;
  if (t < DIM * DIM) woutt[t] = (bf16)Wout[k * DIM + n];
}

// ---------------- kx_ln: LayerNorm(x)*g -> bf16 ----------------
// one row per wave pass, 8 rows per wave. 2048 WGs x 256 thr.
__global__ __launch_bounds__(256) void kx_ln(
    const float* __restrict__ x, const float* __restrict__ gnorm,
    bf16* __restrict__ xn) {
  const int lane = threadIdx.x & 63;
  const int gw = blockIdx.x * 4 + (threadIdx.x >> 6);
  float gv[8];
  #pragma unroll
  for (int j = 0; j < 8; ++j) gv[j] = gnorm[lane * 8 + j];
  #pragma unroll
  for (int i = 0; i < 8; ++i) {
    size_t row = (size_t)gw * 8 + i;
    const float4* xp = (const float4*)(x + row * DIM + lane * 8);
    float4 v0 = xp[0], v1 = xp[1];
    float s  = v0.x + v0.y + v0.z + v0.w + v1.x + v1.y + v1.z + v1.w;
    float sq = v0.x*v0.x + v0.y*v0.y + v0.z*v0.z + v0.w*v0.w
             + v1.x*v1.x + v1.y*v1.y + v1.z*v1.z + v1.w*v1.w;
    #pragma unroll
    for (int d = 1; d < 64; d <<= 1) { s += __shfl_xor(s, d); sq += __shfl_xor(sq, d); }
    float mean = s * (1.f / 512.f);
    float var  = sq * (1.f / 512.f) - mean * mean;
    float rs   = rsqrtf(var + 1e-5f);
    bf16x8 o;
    o[0] = (bf16)((v0.x - mean) * rs * gv[0]);
    o[1] = (bf16)((v0.y - mean) * rs * gv[1]);
    o[2] = (bf16)((v0.z - mean) * rs * gv[2]);
    o[3] = (bf16)((v0.w - mean) * rs * gv[3]);
    o[4] = (bf16)((v1.x - mean) * rs * gv[4]);
    o[5] = (bf16)((v1.y - mean) * rs * gv[5]);
    o[6] = (bf16)((v1.z - mean) * rs * gv[6]);
    o[7] = (bf16)((v1.w - mean) * rs * gv[7]);
    *(bf16x8*)(xn + row * DIM + lane * 8) = o;
  }
}

// ---------------- m97-style GEMM: C[M,NALL] = xn @ wall^T ----------------
// BM=BN=128, BK=32, 256 thr (2x2 waves, 4x4 frags), A+B gload_lds dbuf.
__global__ __launch_bounds__(256) void k_gemm_qkv(
    const bf16* __restrict__ xn, const bf16* __restrict__ wall,
    bf16* __restrict__ qbuf, bf16* __restrict__ kbuf, bf16* __restrict__ vbuf) {
  __shared__ bf16 sa[2][128 * 32];
  __shared__ bf16 sb[2][128 * 32];
  const int t = threadIdx.x, wave = t >> 6, lane = t & 63;
  const int l15 = lane & 15, g = lane >> 4;
  const int wm = wave >> 1, wn = wave & 1;
  // bijective XCD swizzle, nwg=2560=8*320; bn inner for A-tile L2 reuse
  int wg = (blockIdx.x & 7) * 320 + (blockIdx.x >> 3);
  const int bm = wg / 5, bn = wg % 5;
  const char* Abase = (const char*)(xn   + (size_t)bm * 128 * DIM);
  const char* Bbase = (const char*)(wall + (size_t)bn * 128 * DIM);
  const int srow0 = wave * 16 + (lane >> 2);
  const int skb   = (lane & 3) * 16;

  // prologue: stage step 0
  #pragma unroll
  for (int c = 0; c < 2; ++c) {
    int row = c * 64 + srow0;
    int kb = skb ^ ((row & 3) << 4);
    gload_lds16(Abase + (size_t)row * 1024 + kb, (char*)&sa[0][0] + c * 4096 + wave * 1024);
    gload_lds16(Bbase + (size_t)row * 1024 + kb, (char*)&sb[0][0] + c * 4096 + wave * 1024);
  }
  __syncthreads();

  f32x4 acc[4][4];
  #pragma unroll
  for (int mi = 0; mi < 4; ++mi)
    #pragma unroll
    for (int ni = 0; ni < 4; ++ni) acc[mi][ni] = fzero4();

  #pragma unroll 2
  for (int step = 0; step < 16; ++step) {
    const int cur = step & 1;
    if (step < 15) {
      int kk2 = (step + 1) * 64;   // byte offset of next k-slab
      #pragma unroll
      for (int c = 0; c < 2; ++c) {
        int row = c * 64 + srow0;
        int kb = skb ^ ((row & 3) << 4);
        gload_lds16(Abase + (size_t)row * 1024 + kk2 + kb,
                    (char*)&sa[cur ^ 1][0] + c * 4096 + wave * 1024);
        gload_lds16(Bbase + (size_t)row * 1024 + kk2 + kb,
                    (char*)&sb[cur ^ 1][0] + c * 4096 + wave * 1024);
      }
    }
    bf16x8 a[4], b[4];
    #pragma unroll
    for (int mi = 0; mi < 4; ++mi) {
      int row = wm * 64 + mi * 16 + l15;
      a[mi] = *(const bf16x8*)((const char*)&sa[cur][0] + row * 64 + ((g * 16) ^ ((row & 3) << 4)));
    }
    #pragma unroll
    for (int ni = 0; ni < 4; ++ni) {
      int row = wn * 64 + ni * 16 + l15;
      b[ni] = *(const bf16x8*)((const char*)&sb[cur][0] + row * 64 + ((g * 16) ^ ((row & 3) << 4)));
    }
    #pragma unroll
    for (int mi = 0; mi < 4; ++mi)
      #pragma unroll
      for (int ni = 0; ni < 4; ++ni)
        acc[mi][ni] = mfma16(a[mi], b[ni], acc[mi][ni]);
    __syncthreads();
  }

  // epilogue: route cols to q / k / v
  #pragma unroll
  for (int ni = 0; ni < 4; ++ni) {
    int col0 = bn * 128 + wn * 64 + ni * 16;
    bf16* dst; int ld;
    if (col0 < 512)      { dst = qbuf + col0         + l15; ld = DIM;   }
    else if (col0 < 576) { dst = kbuf + (col0 - 512) + l15; ld = DHEAD; }
    else                 { dst = vbuf + (col0 - 576) + l15; ld = DHEAD; }
    #pragma unroll
    for (int mi = 0; mi < 4; ++mi)
      #pragma unroll
      for (int jj = 0; jj < 4; ++jj) {
        size_t row = (size_t)bm * 128 + wm * 64 + mi * 16 + g * 4 + jj;
        dst[row * ld] = (bf16)acc[mi][ni][jj];
      }
  }
}

// ---------------- m97-style GEMM: obuf[M,512] = abuf @ woutt^T ----------------
__global__ __launch_bounds__(256) void k_gemm_out(
    const bf16* __restrict__ abuf, const bf16* __restrict__ woutt,
    bf16* __restrict__ obuf) {
  __shared__ bf16 sa[2][128 * 32];
  __shared__ bf16 sb[2][128 * 32];
  const int t = threadIdx.x, wave = t >> 6, lane = t & 63;
  const int l15 = lane & 15, g = lane >> 4;
  const int wm = wave >> 1, wn = wave & 1;
  int wg = (blockIdx.x & 7) * 256 + (blockIdx.x >> 3);   // nwg=2048=8*256
  const int bm = wg >> 2, bn = wg & 3;
  const char* Abase = (const char*)(abuf  + (size_t)bm * 128 * DIM);
  const char* Bbase = (const char*)(woutt + (size_t)bn * 128 * DIM);
  const int srow0 = wave * 16 + (lane >> 2);
  const int skb   = (lane & 3) * 16;

  #pragma unroll
  for (int c = 0; c < 2; ++c) {
    int row = c * 64 + srow0;
    int kb = skb ^ ((row & 3) << 4);
    gload_lds16(Abase + (size_t)row * 1024 + kb, (char*)&sa[0][0] + c * 4096 + wave * 1024);
    gload_lds16(Bbase + (size_t)row * 1024 + kb, (char*)&sb[0][0] + c * 4096 + wave * 1024);
  }
  __syncthreads();

  f32x4 acc[4][4];
  #pragma unroll
  for (int mi = 0; mi < 4; ++mi)
    #pragma unroll
    for (int ni = 0; ni < 4; ++ni) acc[mi][ni] = fzero4();

  #pragma unroll 2
  for (int step = 0; step < 16; ++step) {
    const int cur = step & 1;
    if (step < 15) {
      int kk2 = (step + 1) * 64;
      #pragma unroll
      for (int c = 0; c < 2; ++c) {
        int row = c * 64 + srow0;
        int kb = skb ^ ((row & 3) << 4);
        gload_lds16(Abase + (size_t)row * 1024 + kk2 + kb,
                    (char*)&sa[cur ^ 1][0] + c * 4096 + wave * 1024);
        gload_lds16(Bbase + (size_t)row * 1024 + kk2 + kb,
                    (char*)&sb[cur ^ 1][0] + c * 4096 + wave * 1024);
      }
    }
    bf16x8 a[4], b[4];
    #pragma unroll
    for (int mi = 0; mi < 4; ++mi) {
      int row = wm * 64 + mi * 16 + l15;
      a[mi] = *(const bf16x8*)((const char*)&sa[cur][0] + row * 64 + ((g * 16) ^ ((row & 3) << 4)));
    }
    #pragma unroll
    for (int ni = 0; ni < 4; ++ni) {
      int row = wn * 64 + ni * 16 + l15;
      b[ni] = *(const bf16x8*)((const char*)&sb[cur][0] + row * 64 + ((g * 16) ^ ((row & 3) << 4)));
    }
    #pragma unroll
    for (int mi = 0; mi < 4; ++mi)
      #pragma unroll
      for (int ni = 0; ni < 4; ++ni)
        acc[mi][ni] = mfma16(a[mi], b[ni], acc[mi][ni]);
    __syncthreads();
  }

  #pragma unroll
  for (int ni = 0; ni < 4; ++ni) {
    int col = bn * 128 + wn * 64 + ni * 16 + l15;
    #pragma unroll
    for (int mi = 0; mi < 4; ++mi)
      #pragma unroll
      for (int jj = 0; jj < 4; ++jj) {
        size_t row = (size_t)bm * 128 + wm * 64 + mi * 16 + g * 4 + jj;
        obuf[row * DIM + col] = (bf16)acc[mi][ni][jj];
      }
  }
}

// ---------------- k_ln_out: LayerNorm(obuf)*g_out -> f32 ----------------
__global__ __launch_bounds__(256) void k_ln_out(
    const bf16* __restrict__ obuf, const float* __restrict__ gout,
    float* __restrict__ out) {
  const int lane = threadIdx.x & 63;
  const int gw = blockIdx.x * 4 + (threadIdx.x >> 6);
  float gv[8];
  #pragma unroll
  for (int j = 0; j < 8; ++j) gv[j] = gout[lane * 8 + j];
  #pragma unroll
  for (int i = 0; i < 8; ++i) {
    size_t row = (size_t)gw * 8 + i;
    bf16x8 v = *(const bf16x8*)(obuf + row * DIM + lane * 8);
    float f[8];
    float s = 0.f, sq = 0.f;
    #pragma unroll
    for (int j = 0; j < 8; ++j) { f[j] = (float)v[j]; s += f[j]; sq += f[j] * f[j]; }
    #pragma unroll
    for (int d = 1; d < 64; d <<= 1) { s += __shfl_xor(s, d); sq += __shfl_xor(sq, d); }
    float mean = s * (1.f / 512.f);
    float var  = sq * (1.f / 512.f) - mean * mean;
    float rs   = rsqrtf(var + 1e-5f);
    float4 o0, o1;
    o0.x = (f[0]-mean)*rs*gv[0]; o0.y = (f[1]-mean)*rs*gv[1];
    o0.z = (f[2]-mean)*rs*gv[2]; o0.w = (f[3]-mean)*rs*gv[3];
    o1.x = (f[4]-mean)*rs*gv[4]; o1.y = (f[5]-mean)*rs*gv[5];
    o1.z = (f[6]-mean)*rs*gv[6]; o1.w = (f[7]-mean)*rs*gv[7];
    float4* op = (float4*)(out + row * DIM + lane * 8);
    op[0] = o0; op[1] = o1;
  }
}

// ---------------- K2: flash attention per (b*n, head) ----------------
__global__ __launch_bounds__(512) void k_attn(
    bf16* __restrict__ qbuf, const bf16* __restrict__ kbuf,
    const bf16* __restrict__ vbuf) {
  __shared__ bf16 lk[64][64];
  __shared__ bf16 lvt[64][64];
  __shared__ bf16 lp[8][32][64];
  const int t = threadIdx.x, wave = t >> 6, lane = t & 63;
  const int l15 = lane & 15, g = lane >> 4;
  const int bn = blockIdx.x >> 3, h = blockIdx.x & 7;
  const size_t tok0 = (size_t)bn * RLEN;
  const int m0 = wave * 32;

  bf16x8 aq[2][2];
  {
    const bf16* qb = qbuf + (tok0 + m0 + l15) * DIM + h * DHEAD + g * 8;
    #pragma unroll
    for (int mi = 0; mi < 2; ++mi)
      #pragma unroll
      for (int ks = 0; ks < 2; ++ks)
        aq[mi][ks] = *(const bf16x8*)(qb + (size_t)mi * 16 * DIM + ks * 32);
  }
  f32x4 o[2][4];
  float mrow[2][4], lrow[2][4];
  #pragma unroll
  for (int mi = 0; mi < 2; ++mi) {
    #pragma unroll
    for (int di = 0; di < 4; ++di) o[mi][di] = fzero4();
    #pragma unroll
    for (int jj = 0; jj < 4; ++jj) { mrow[mi][jj] = -1e30f; lrow[mi][jj] = 0.f; }
  }

  for (int j = 0; j < 4; ++j) {
    __syncthreads();
    {
      const bf16* kc = kbuf + (tok0 + j * 64) * DHEAD;
      int r = t >> 3, c8 = (t & 7) * 8;
      *(bf16x8*)&lk[r][c8 ^ ((r & 7) << 3)] = *(const bf16x8*)(kc + r * DHEAD + c8);
      const bf16* vc = vbuf + (tok0 + j * 64) * DHEAD;
      int c = t & 63;
      #pragma unroll
      for (int i = 0; i < 8; ++i) {
        int rr = (t >> 6) + i * 8;
        lvt[c][rr ^ ((c & 7) << 3)] = vc[rr * DHEAD + c];
      }
    }
    __syncthreads();

    f32x4 s[2][4];
    #pragma unroll
    for (int mi = 0; mi < 2; ++mi)
      #pragma unroll
      for (int nj = 0; nj < 4; ++nj) s[mi][nj] = fzero4();
    #pragma unroll
    for (int ks = 0; ks < 2; ++ks) {
      bf16x8 bk[4];
      #pragma unroll
      for (int nj = 0; nj < 4; ++nj)
        bk[nj] = *(const bf16x8*)&lk[nj * 16 + l15][(ks * 32 + g * 8) ^ ((l15 & 7) << 3)];
      #pragma unroll
      for (int mi = 0; mi < 2; ++mi)
        #pragma unroll
        for (int nj = 0; nj < 4; ++nj)
          s[mi][nj] = mfma16(aq[mi][ks], bk[nj], s[mi][nj]);
    }

    #pragma unroll
    for (int mi = 0; mi < 2; ++mi) {
      #pragma unroll
      for (int jj = 0; jj < 4; ++jj) {
        float s0 = s[mi][0][jj] * 0.125f;
        float s1 = s[mi][1][jj] * 0.125f;
        float s2 = s[mi][2][jj] * 0.125f;
        float s3 = s[mi][3][jj] * 0.125f;
        float cm = fmaxf(fmaxf(s0, s1), fmaxf(s2, s3));
        cm = fmaxf(cm, __shfl_xor(cm, 1));
        cm = fmaxf(cm, __shfl_xor(cm, 2));
        cm = fmaxf(cm, __shfl_xor(cm, 4));
        cm = fmaxf(cm, __shfl_xor(cm, 8));
        float mold = mrow[mi][jj];
        float mnew = fmaxf(mold, cm);
        float alpha = __expf(mold - mnew);
        mrow[mi][jj] = mnew;
        float p0 = __expf(s0 - mnew), p1 = __expf(s1 - mnew);
        float p2 = __expf(s2 - mnew), p3 = __expf(s3 - mnew);
        float ps = p0 + p1 + p2 + p3;
        ps += __shfl_xor(ps, 1); ps += __shfl_xor(ps, 2);
        ps += __shfl_xor(ps, 4); ps += __shfl_xor(ps, 8);
        lrow[mi][jj] = lrow[mi][jj] * alpha + ps;
        #pragma unroll
        for (int di = 0; di < 4; ++di) o[mi][di][jj] *= alpha;
        int prow = mi * 16 + g * 4 + jj;
        int sw = (prow & 7) << 3;
        lp[wave][prow][( 0 + l15) ^ sw] = (bf16)p0;
        lp[wave][prow][(16 + l15) ^ sw] = (bf16)p1;
        lp[wave][prow][(32 + l15) ^ sw] = (bf16)p2;
        lp[wave][prow][(48 + l15) ^ sw] = (bf16)p3;
      }
    }
    __syncthreads();

    #pragma unroll
    for (int ks = 0; ks < 2; ++ks) {
      bf16x8 pa[2], bv[4];
      #pragma unroll
      for (int mi = 0; mi < 2; ++mi)
        pa[mi] = *(const bf16x8*)&lp[wave][mi * 16 + l15][(ks * 32 + g * 8) ^ ((l15 & 7) << 3)];
      #pragma unroll
      for (int di = 0; di < 4; ++di)
        bv[di] = *(const bf16x8*)&lvt[di * 16 + l15][(ks * 32 + g * 8) ^ ((l15 & 7) << 3)];
      #pragma unroll
      for (int mi = 0; mi < 2; ++mi)
        #pragma unroll
        for (int di = 0; di < 4; ++di)
          o[mi][di] = mfma16(pa[mi], bv[di], o[mi][di]);
    }
  }

  #pragma unroll
  for (int mi = 0; mi < 2; ++mi)
    #pragma unroll
    for (int jj = 0; jj < 4; ++jj) {
      float inv = 1.0f / lrow[mi][jj];
      size_t row = tok0 + m0 + mi * 16 + g * 4 + jj;
      #pragma unroll
      for (int di = 0; di < 4; ++di)
        qbuf[row * DIM + h * DHEAD + di * 16 + l15] = (bf16)(o[mi][di][jj] * inv);
    }
}

// ---------------- launch ----------------
extern "C" void kernel_launch(void* const* d_in, const int* in_sizes, int n_in,
                              void* d_out, int out_size, void* d_ws, size_t ws_size,
                              hipStream_t stream) {
  const float* x     = (const float*)d_in[0];
  const float* gnorm = (const float*)d_in[1];
  const float* Wq    = (const float*)d_in[2];
  const float* Wkv   = (const float*)d_in[3];
  const float* Wout  = (const float*)d_in[4];
  const float* gout  = (const float*)d_in[5];
  float* out = (float*)d_out;
  char* ws = (char*)d_ws;
  // ws: wall 640K | woutt 512K | xnbuf/obuf 64M (aliased) | qbuf 64M | kbuf 8M | vbuf 8M
  bf16* wall  = (bf16*)(ws);
  bf16* woutt = (bf16*)(ws + 655360);
  bf16* xnbuf = (bf16*)(ws + 1179648);
  bf16* obuf  = xnbuf;   // xn dead after k_gemm_qkv
  bf16* qbuf  = (bf16*)(ws + 1179648 + (size_t)TOK * DIM * 2);
  bf16* kbuf  = (bf16*)((char*)qbuf + (size_t)TOK * DIM * 2);
  bf16* vbuf  = (bf16*)((char*)kbuf + (size_t)TOK * DHEAD * 2);

  k_prep    <<<dim3(1280), dim3(256), 0, stream>>>(Wq, Wkv, Wout, wall, woutt);
  kx_ln     <<<dim3(2048), dim3(256), 0, stream>>>(x, gnorm, xnbuf);
  k_gemm_qkv<<<dim3(2560), dim3(256), 0, stream>>>(xnbuf, wall, qbuf, kbuf, vbuf);
  k_attn    <<<dim3(2048), dim3(512), 0, stream>>>(qbuf, kbuf, vbuf);
  k_gemm_out<<<dim3(2048), dim3(256), 0, stream>>>(qbuf, woutt, obuf);
  k_ln_out  <<<dim3(2048), dim3(256), 0, stream>>>(obuf, gout, out);
}

// Round 5
// 297.510 us; speedup vs baseline: 1.2523x; 1.0863x over previous
//
#include <hip/hip_runtime.h>
#include <stdint.h>

// Pipeline: kx_ln | k_gemm_qkv (m97 128x128, writes q,k,vT) | k_attn (1-barrier
// exact-softmax flash) | k_gemm_out (m97) | k_ln_out
// x[4,64,256,512]; heads=8, dhead=64.

#define DIM   512
#define DHEAD 64
#define RLEN  256
#define TOK   65536
#define NALL  640

typedef __bf16 bf16;
typedef __bf16 bf16x4 __attribute__((ext_vector_type(4)));
typedef __bf16 bf16x8 __attribute__((ext_vector_type(8)));
typedef float  f32x4  __attribute__((ext_vector_type(4)));

__device__ __forceinline__ f32x4 mfma16(bf16x8 a, bf16x8 b, f32x4 c) {
  return __builtin_amdgcn_mfma_f32_16x16x32_bf16(a, b, c, 0, 0, 0);
}
__device__ __forceinline__ f32x4 fzero4() {
  f32x4 z; z[0] = z[1] = z[2] = z[3] = 0.f; return z;
}
__device__ __forceinline__ void gload_lds16(const void* g, void* l) {
  __builtin_amdgcn_global_load_lds(
      (const __attribute__((address_space(1))) void*)g,
      (__attribute__((address_space(3))) void*)l, 16, 0, 0);
}

// ---------------- K0: weights -> bf16, [n][k] layout ----------------
__global__ __launch_bounds__(256) void k_prep(
    const float* __restrict__ Wq, const float* __restrict__ Wkv,
    const float* __restrict__ Wout,
    bf16* __restrict__ wall, bf16* __restrict__ woutt) {
  int t = blockIdx.x * 256 + threadIdx.x;   // grid covers 640*512
  int n = t >> 9, k = t & 511;
  float v = (n < DIM) ? Wq[k * DIM + n] : Wkv[k * 128 + (n - DIM)];
  wall[t] = (bf16)v;
  if (t < DIM * DIM) woutt[t] = (bf16)Wout[k * DIM + n];
}

// ---------------- kx_ln: LayerNorm(x)*g -> bf16 ----------------
__global__ __launch_bounds__(256) void kx_ln(
    const float* __restrict__ x, const float* __restrict__ gnorm,
    bf16* __restrict__ xn) {
  const int lane = threadIdx.x & 63;
  const int gw = blockIdx.x * 4 + (threadIdx.x >> 6);
  float gv[8];
  #pragma unroll
  for (int j = 0; j < 8; ++j) gv[j] = gnorm[lane * 8 + j];
  #pragma unroll
  for (int i = 0; i < 8; ++i) {
    size_t row = (size_t)gw * 8 + i;
    const float4* xp = (const float4*)(x + row * DIM + lane * 8);
    float4 v0 = xp[0], v1 = xp[1];
    float s  = v0.x + v0.y + v0.z + v0.w + v1.x + v1.y + v1.z + v1.w;
    float sq = v0.x*v0.x + v0.y*v0.y + v0.z*v0.z + v0.w*v0.w
             + v1.x*v1.x + v1.y*v1.y + v1.z*v1.z + v1.w*v1.w;
    #pragma unroll
    for (int d = 1; d < 64; d <<= 1) { s += __shfl_xor(s, d); sq += __shfl_xor(sq, d); }
    float mean = s * (1.f / 512.f);
    float var  = sq * (1.f / 512.f) - mean * mean;
    float rs   = rsqrtf(var + 1e-5f);
    bf16x8 o;
    o[0] = (bf16)((v0.x - mean) * rs * gv[0]);
    o[1] = (bf16)((v0.y - mean) * rs * gv[1]);
    o[2] = (bf16)((v0.z - mean) * rs * gv[2]);
    o[3] = (bf16)((v0.w - mean) * rs * gv[3]);
    o[4] = (bf16)((v1.x - mean) * rs * gv[4]);
    o[5] = (bf16)((v1.y - mean) * rs * gv[5]);
    o[6] = (bf16)((v1.z - mean) * rs * gv[6]);
    o[7] = (bf16)((v1.w - mean) * rs * gv[7]);
    *(bf16x8*)(xn + row * DIM + lane * 8) = o;
  }
}

// ---------------- m97-style GEMM: [M,640] = xn @ wall^T -> q,k,vT ----------
__global__ __launch_bounds__(256) void k_gemm_qkv(
    const bf16* __restrict__ xn, const bf16* __restrict__ wall,
    bf16* __restrict__ qbuf, bf16* __restrict__ kbuf, bf16* __restrict__ vtbuf) {
  __shared__ bf16 sa[2][128 * 32];
  __shared__ bf16 sb[2][128 * 32];
  const int t = threadIdx.x, wave = t >> 6, lane = t & 63;
  const int l15 = lane & 15, g = lane >> 4;
  const int wm = wave >> 1, wn = wave & 1;
  int wg = (blockIdx.x & 7) * 320 + (blockIdx.x >> 3);   // nwg=2560=8*320
  const int bm = wg / 5, bn = wg % 5;
  const char* Abase = (const char*)(xn   + (size_t)bm * 128 * DIM);
  const char* Bbase = (const char*)(wall + (size_t)bn * 128 * DIM);
  const int srow0 = wave * 16 + (lane >> 2);
  const int skb   = (lane & 3) * 16;

  #pragma unroll
  for (int c = 0; c < 2; ++c) {
    int row = c * 64 + srow0;
    int kb = skb ^ ((row & 3) << 4);
    gload_lds16(Abase + (size_t)row * 1024 + kb, (char*)&sa[0][0] + c * 4096 + wave * 1024);
    gload_lds16(Bbase + (size_t)row * 1024 + kb, (char*)&sb[0][0] + c * 4096 + wave * 1024);
  }
  __syncthreads();

  f32x4 acc[4][4];
  #pragma unroll
  for (int mi = 0; mi < 4; ++mi)
    #pragma unroll
    for (int ni = 0; ni < 4; ++ni) acc[mi][ni] = fzero4();

  #pragma unroll 2
  for (int step = 0; step < 16; ++step) {
    const int cur = step & 1;
    if (step < 15) {
      int kk2 = (step + 1) * 64;
      #pragma unroll
      for (int c = 0; c < 2; ++c) {
        int row = c * 64 + srow0;
        int kb = skb ^ ((row & 3) << 4);
        gload_lds16(Abase + (size_t)row * 1024 + kk2 + kb,
                    (char*)&sa[cur ^ 1][0] + c * 4096 + wave * 1024);
        gload_lds16(Bbase + (size_t)row * 1024 + kk2 + kb,
                    (char*)&sb[cur ^ 1][0] + c * 4096 + wave * 1024);
      }
    }
    bf16x8 a[4], b[4];
    #pragma unroll
    for (int mi = 0; mi < 4; ++mi) {
      int row = wm * 64 + mi * 16 + l15;
      a[mi] = *(const bf16x8*)((const char*)&sa[cur][0] + row * 64 + ((g * 16) ^ ((row & 3) << 4)));
    }
    #pragma unroll
    for (int ni = 0; ni < 4; ++ni) {
      int row = wn * 64 + ni * 16 + l15;
      b[ni] = *(const bf16x8*)((const char*)&sb[cur][0] + row * 64 + ((g * 16) ^ ((row & 3) << 4)));
    }
    #pragma unroll
    for (int mi = 0; mi < 4; ++mi)
      #pragma unroll
      for (int ni = 0; ni < 4; ++ni)
        acc[mi][ni] = mfma16(a[mi], b[ni], acc[mi][ni]);
    __syncthreads();
  }

  // epilogue: route cols to q / k / vT
  #pragma unroll
  for (int ni = 0; ni < 4; ++ni) {
    int col0 = bn * 128 + wn * 64 + ni * 16;
    if (col0 < 512) {
      bf16* dst = qbuf + col0 + l15;
      #pragma unroll
      for (int mi = 0; mi < 4; ++mi)
        #pragma unroll
        for (int jj = 0; jj < 4; ++jj) {
          size_t row = (size_t)bm * 128 + wm * 64 + mi * 16 + g * 4 + jj;
          dst[row * DIM] = (bf16)acc[mi][ni][jj];
        }
    } else if (col0 < 576) {
      bf16* dst = kbuf + (col0 - 512) + l15;
      #pragma unroll
      for (int mi = 0; mi < 4; ++mi)
        #pragma unroll
        for (int jj = 0; jj < 4; ++jj) {
          size_t row = (size_t)bm * 128 + wm * 64 + mi * 16 + g * 4 + jj;
          dst[row * DHEAD] = (bf16)acc[mi][ni][jj];
        }
    } else {
      // vT[bn_r][d][kv]: jj is kv-contiguous -> packed b64 store
      int d = col0 - 576 + l15;
      #pragma unroll
      for (int mi = 0; mi < 4; ++mi) {
        size_t row = (size_t)bm * 128 + wm * 64 + mi * 16 + g * 4;
        int bnr = (int)(row >> 8), kv = (int)(row & 255);
        bf16x4 v4;
        v4[0] = (bf16)acc[mi][ni][0]; v4[1] = (bf16)acc[mi][ni][1];
        v4[2] = (bf16)acc[mi][ni][2]; v4[3] = (bf16)acc[mi][ni][3];
        *(bf16x4*)(vtbuf + (size_t)bnr * 16384 + (size_t)d * 256 + kv) = v4;
      }
    }
  }
}

// ---------------- m97-style GEMM: obuf[M,512] = abuf @ woutt^T ----------------
__global__ __launch_bounds__(256) void k_gemm_out(
    const bf16* __restrict__ abuf, const bf16* __restrict__ woutt,
    bf16* __restrict__ obuf) {
  __shared__ bf16 sa[2][128 * 32];
  __shared__ bf16 sb[2][128 * 32];
  const int t = threadIdx.x, wave = t >> 6, lane = t & 63;
  const int l15 = lane & 15, g = lane >> 4;
  const int wm = wave >> 1, wn = wave & 1;
  int wg = (blockIdx.x & 7) * 256 + (blockIdx.x >> 3);   // nwg=2048=8*256
  const int bm = wg >> 2, bn = wg & 3;
  const char* Abase = (const char*)(abuf  + (size_t)bm * 128 * DIM);
  const char* Bbase = (const char*)(woutt + (size_t)bn * 128 * DIM);
  const int srow0 = wave * 16 + (lane >> 2);
  const int skb   = (lane & 3) * 16;

  #pragma unroll
  for (int c = 0; c < 2; ++c) {
    int row = c * 64 + srow0;
    int kb = skb ^ ((row & 3) << 4);
    gload_lds16(Abase + (size_t)row * 1024 + kb, (char*)&sa[0][0] + c * 4096 + wave * 1024);
    gload_lds16(Bbase + (size_t)row * 1024 + kb, (char*)&sb[0][0] + c * 4096 + wave * 1024);
  }
  __syncthreads();

  f32x4 acc[4][4];
  #pragma unroll
  for (int mi = 0; mi < 4; ++mi)
    #pragma unroll
    for (int ni = 0; ni < 4; ++ni) acc[mi][ni] = fzero4();

  #pragma unroll 2
  for (int step = 0; step < 16; ++step) {
    const int cur = step & 1;
    if (step < 15) {
      int kk2 = (step + 1) * 64;
      #pragma unroll
      for (int c = 0; c < 2; ++c) {
        int row = c * 64 + srow0;
        int kb = skb ^ ((row & 3) << 4);
        gload_lds16(Abase + (size_t)row * 1024 + kk2 + kb,
                    (char*)&sa[cur ^ 1][0] + c * 4096 + wave * 1024);
        gload_lds16(Bbase + (size_t)row * 1024 + kk2 + kb,
                    (char*)&sb[cur ^ 1][0] + c * 4096 + wave * 1024);
      }
    }
    bf16x8 a[4], b[4];
    #pragma unroll
    for (int mi = 0; mi < 4; ++mi) {
      int row = wm * 64 + mi * 16 + l15;
      a[mi] = *(const bf16x8*)((const char*)&sa[cur][0] + row * 64 + ((g * 16) ^ ((row & 3) << 4)));
    }
    #pragma unroll
    for (int ni = 0; ni < 4; ++ni) {
      int row = wn * 64 + ni * 16 + l15;
      b[ni] = *(const bf16x8*)((const char*)&sb[cur][0] + row * 64 + ((g * 16) ^ ((row & 3) << 4)));
    }
    #pragma unroll
    for (int mi = 0; mi < 4; ++mi)
      #pragma unroll
      for (int ni = 0; ni < 4; ++ni)
        acc[mi][ni] = mfma16(a[mi], b[ni], acc[mi][ni]);
    __syncthreads();
  }

  #pragma unroll
  for (int ni = 0; ni < 4; ++ni) {
    int col = bn * 128 + wn * 64 + ni * 16 + l15;
    #pragma unroll
    for (int mi = 0; mi < 4; ++mi)
      #pragma unroll
      for (int jj = 0; jj < 4; ++jj) {
        size_t row = (size_t)bm * 128 + wm * 64 + mi * 16 + g * 4 + jj;
        obuf[row * DIM + col] = (bf16)acc[mi][ni][jj];
      }
  }
}

// ---------------- k_ln_out: LayerNorm(obuf)*g_out -> f32 ----------------
__global__ __launch_bounds__(256) void k_ln_out(
    const bf16* __restrict__ obuf, const float* __restrict__ gout,
    float* __restrict__ out) {
  const int lane = threadIdx.x & 63;
  const int gw = blockIdx.x * 4 + (threadIdx.x >> 6);
  float gv[8];
  #pragma unroll
  for (int j = 0; j < 8; ++j) gv[j] = gout[lane * 8 + j];
  #pragma unroll
  for (int i = 0; i < 8; ++i) {
    size_t row = (size_t)gw * 8 + i;
    bf16x8 v = *(const bf16x8*)(obuf + row * DIM + lane * 8);
    float f[8];
    float s = 0.f, sq = 0.f;
    #pragma unroll
    for (int j = 0; j < 8; ++j) { f[j] = (float)v[j]; s += f[j]; sq += f[j] * f[j]; }
    #pragma unroll
    for (int d = 1; d < 64; d <<= 1) { s += __shfl_xor(s, d); sq += __shfl_xor(sq, d); }
    float mean = s * (1.f / 512.f);
    float var  = sq * (1.f / 512.f) - mean * mean;
    float rs   = rsqrtf(var + 1e-5f);
    float4 o0, o1;
    o0.x = (f[0]-mean)*rs*gv[0]; o0.y = (f[1]-mean)*rs*gv[1];
    o0.z = (f[2]-mean)*rs*gv[2]; o0.w = (f[3]-mean)*rs*gv[3];
    o1.x = (f[4]-mean)*rs*gv[4]; o1.y = (f[5]-mean)*rs*gv[5];
    o1.z = (f[6]-mean)*rs*gv[6]; o1.w = (f[7]-mean)*rs*gv[7];
    float4* op = (float4*)(out + row * DIM + lane * 8);
    op[0] = o0; op[1] = o1;
  }
}

// ---------------- k_attn: exact-softmax flash, 1 barrier per block ---------
// 512 thr (8 waves x 32 q-rows). K[256][64] + V^T[64][256] staged once via
// global_load_lds (XOR pre-swizzled source, swizzled reads). S full-width in
// regs; exp deferred into PV chunks; per-wave P tile in LDS (no barriers).
__global__ __launch_bounds__(512, 2) void k_attn(
    bf16* __restrict__ qbuf, const bf16* __restrict__ kbuf,
    const bf16* __restrict__ vtbuf) {
  __shared__ bf16 lk[256 * 64];     // 32 KB: [kv][d], 16B-unit swizzle u^=(row&7)
  __shared__ bf16 lvt[64 * 256];    // 32 KB: [d][kv], unit swizzle u^=(row&7)
  __shared__ bf16 lp[8][32 * 64];   // 32 KB: per-wave P chunk [q][kv64]
  const int t = threadIdx.x, wave = t >> 6, lane = t & 63;
  const int l15 = lane & 15, g = lane >> 4;
  int wg = (blockIdx.x & 7) * 256 + (blockIdx.x >> 3);  // 8 heads of a bn on one XCD
  const int bn = wg >> 3, h = wg & 7;
  const size_t tok0 = (size_t)bn * RLEN;
  const int m0 = wave * 32;

  // ---- stage K and V^T (async DMA; source pre-swizzled, LDS linear)
  {
    const char* ksrc = (const char*)(kbuf + tok0 * DHEAD);
    const char* vsrc = (const char*)(vtbuf + (size_t)bn * 64 * 256);
    #pragma unroll
    for (int i = 0; i < 4; ++i) {
      int d = i * 8192 + wave * 1024 + lane * 16;
      int krow = d >> 7, ku = (d >> 4) & 7;
      gload_lds16(ksrc + (krow << 7) + ((ku ^ (krow & 7)) << 4),
                  (char*)lk + i * 8192 + wave * 1024);
      int vrow = d >> 9, vu = (d >> 4) & 31;
      gload_lds16(vsrc + (vrow << 9) + ((vu ^ (vrow & 7)) << 4),
                  (char*)lvt + i * 8192 + wave * 1024);
    }
  }
  // Q fragments (independent global loads, overlap the DMA)
  bf16x8 aq[2][2];
  {
    const bf16* qb = qbuf + (tok0 + m0 + l15) * DIM + h * DHEAD + g * 8;
    #pragma unroll
    for (int mi = 0; mi < 2; ++mi)
      #pragma unroll
      for (int ks = 0; ks < 2; ++ks)
        aq[mi][ks] = *(const bf16x8*)(qb + (size_t)mi * 16 * DIM + ks * 32);
  }
  __syncthreads();   // single barrier: K/V^T in LDS

  // ---- S = Q K^T, full 256 kv in registers
  f32x4 s[2][16];
  #pragma unroll
  for (int mi = 0; mi < 2; ++mi)
    #pragma unroll
    for (int nj = 0; nj < 16; ++nj) s[mi][nj] = fzero4();
  #pragma unroll
  for (int nj = 0; nj < 16; ++nj) {
    int row = l15 + 16 * nj;
    const char* lkb = (const char*)lk + (row << 7);
    int sw = (row & 7) << 4;
    bf16x8 bk0 = *(const bf16x8*)(lkb + ((g << 4) ^ sw));
    bf16x8 bk1 = *(const bf16x8*)(lkb + (((4 + g) << 4) ^ sw));
    s[0][nj] = mfma16(aq[0][0], bk0, s[0][nj]);
    s[0][nj] = mfma16(aq[0][1], bk1, s[0][nj]);
    s[1][nj] = mfma16(aq[1][0], bk0, s[1][nj]);
    s[1][nj] = mfma16(aq[1][1], bk1, s[1][nj]);
  }

  // ---- exact row max (in-lane over 16 frags + 4 shfl over l15 group)
  float mrow[2][4], lsum[2][4];
  #pragma unroll
  for (int mi = 0; mi < 2; ++mi)
    #pragma unroll
    for (int jj = 0; jj < 4; ++jj) {
      float m = s[mi][0][jj];
      #pragma unroll
      for (int nj = 1; nj < 16; ++nj) m = fmaxf(m, s[mi][nj][jj]);
      m = fmaxf(m, __shfl_xor(m, 1));
      m = fmaxf(m, __shfl_xor(m, 2));
      m = fmaxf(m, __shfl_xor(m, 4));
      m = fmaxf(m, __shfl_xor(m, 8));
      mrow[mi][jj] = m;
      lsum[mi][jj] = 0.f;
    }

  // ---- PV over 4 chunks of 64 kv: exp + P->lp + 2x(pa,bv reads + 8 MFMA)
  const float C = 0.1803368801f;   // 0.125 * log2(e)
  f32x4 o[2][4];
  #pragma unroll
  for (int mi = 0; mi < 2; ++mi)
    #pragma unroll
    for (int di = 0; di < 4; ++di) o[mi][di] = fzero4();

  char* lpw = (char*)&lp[wave][0];
  #pragma unroll
  for (int c = 0; c < 4; ++c) {
    #pragma unroll
    for (int mi = 0; mi < 2; ++mi)
      #pragma unroll
      for (int u = 0; u < 4; ++u) {
        int kvl = l15 + 16 * u;
        #pragma unroll
        for (int jj = 0; jj < 4; ++jj) {
          float p = exp2f((s[mi][4 * c + u][jj] - mrow[mi][jj]) * C);
          lsum[mi][jj] += p;
          int q = 16 * mi + 4 * g + jj;
          int unit = (kvl >> 3) ^ (q & 7);
          *(bf16*)(lpw + (q << 7) + (unit << 4) + ((kvl & 7) << 1)) = (bf16)p;
        }
      }
    #pragma unroll
    for (int ks = 0; ks < 2; ++ks) {
      bf16x8 pa[2], bv[4];
      #pragma unroll
      for (int mi = 0; mi < 2; ++mi) {
        int q = l15 + 16 * mi;
        pa[mi] = *(const bf16x8*)(lpw + (q << 7) + ((((4 * ks + g) << 4)) ^ ((q & 7) << 4)));
      }
      #pragma unroll
      for (int di = 0; di < 4; ++di) {
        int row = l15 + 16 * di;
        int unit = 8 * c + 4 * ks + g;
        bv[di] = *(const bf16x8*)((const char*)lvt + (row << 9) + ((unit ^ (row & 7)) << 4));
      }
      #pragma unroll
      for (int mi = 0; mi < 2; ++mi)
        #pragma unroll
        for (int di = 0; di < 4; ++di)
          o[mi][di] = mfma16(pa[mi], bv[di], o[mi][di]);
    }
  }

  // ---- normalize and write back in place
  #pragma unroll
  for (int mi = 0; mi < 2; ++mi)
    #pragma unroll
    for (int jj = 0; jj < 4; ++jj) {
      float l = lsum[mi][jj];
      l += __shfl_xor(l, 1); l += __shfl_xor(l, 2);
      l += __shfl_xor(l, 4); l += __shfl_xor(l, 8);
      float inv = 1.0f / l;
      size_t row = tok0 + m0 + mi * 16 + g * 4 + jj;
      #pragma unroll
      for (int di = 0; di < 4; ++di)
        qbuf[row * DIM + h * DHEAD + di * 16 + l15] = (bf16)(o[mi][di][jj] * inv);
    }
}

// ---------------- launch ----------------
extern "C" void kernel_launch(void* const* d_in, const int* in_sizes, int n_in,
                              void* d_out, int out_size, void* d_ws, size_t ws_size,
                              hipStream_t stream) {
  const float* x     = (const float*)d_in[0];
  const float* gnorm = (const float*)d_in[1];
  const float* Wq    = (const float*)d_in[2];
  const float* Wkv   = (const float*)d_in[3];
  const float* Wout  = (const float*)d_in[4];
  const float* gout  = (const float*)d_in[5];
  float* out = (float*)d_out;
  char* ws = (char*)d_ws;
  // ws: wall 640K | woutt 512K | xnbuf/obuf 64M (aliased) | qbuf 64M | kbuf 8M | vtbuf 8M
  bf16* wall  = (bf16*)(ws);
  bf16* woutt = (bf16*)(ws + 655360);
  bf16* xnbuf = (bf16*)(ws + 1179648);
  bf16* obuf  = xnbuf;   // xn dead after k_gemm_qkv
  bf16* qbuf  = (bf16*)(ws + 1179648 + (size_t)TOK * DIM * 2);
  bf16* kbuf  = (bf16*)((char*)qbuf + (size_t)TOK * DIM * 2);
  bf16* vtbuf = (bf16*)((char*)kbuf + (size_t)TOK * DHEAD * 2);

  k_prep    <<<dim3(1280), dim3(256), 0, stream>>>(Wq, Wkv, Wout, wall, woutt);
  kx_ln     <<<dim3(2048), dim3(256), 0, stream>>>(x, gnorm, xnbuf);
  k_gemm_qkv<<<dim3(2560), dim3(256), 0, stream>>>(xnbuf, wall, qbuf, kbuf, vtbuf);
  k_attn    <<<dim3(2048), dim3(512), 0, stream>>>(qbuf, kbuf, vtbuf);
  k_gemm_out<<<dim3(2048), dim3(256), 0, stream>>>(qbuf, woutt, obuf);
  k_ln_out  <<<dim3(2048), dim3(256), 0, stream>>>(obuf, gout, out);
}

// Round 6
// 282.798 us; speedup vs baseline: 1.3175x; 1.0520x over previous
//
#include <hip/hip_runtime.h>
#include <stdint.h>

// Pipeline: kx_ln | k_gemm_qkv (m97 128x128, writes q,k,vT) | k_attn (swapped
// QK^T, register-resident P, K=16 PV) | k_gemm_out (m97) | k_ln_out
// x[4,64,256,512]; heads=8, dhead=64.

#define DIM   512
#define DHEAD 64
#define RLEN  256
#define TOK   65536
#define NALL  640

typedef __bf16 bf16;
typedef __bf16 bf16x4 __attribute__((ext_vector_type(4)));
typedef __bf16 bf16x8 __attribute__((ext_vector_type(8)));
typedef float  f32x4  __attribute__((ext_vector_type(4)));
typedef short  s16x4  __attribute__((ext_vector_type(4)));

__device__ __forceinline__ f32x4 mfma16(bf16x8 a, bf16x8 b, f32x4 c) {
  return __builtin_amdgcn_mfma_f32_16x16x32_bf16(a, b, c, 0, 0, 0);
}
// K=16 MFMA: A-frag = 4 bf16 (lane: row=l&15, k=4*(l>>4)+j)
__device__ __forceinline__ f32x4 mfma_k16(bf16x4 a, bf16x4 b, f32x4 c) {
#if __has_builtin(__builtin_amdgcn_mfma_f32_16x16x16bf16_1k)
  return __builtin_amdgcn_mfma_f32_16x16x16bf16_1k(
      __builtin_bit_cast(s16x4, a), __builtin_bit_cast(s16x4, b), c, 0, 0, 0);
#else
  f32x4 d = c;
  asm volatile("v_mfma_f32_16x16x16_bf16 %0, %1, %2, %0"
               : "+v"(d) : "v"(a), "v"(b));
  return d;
#endif
}
__device__ __forceinline__ f32x4 fzero4() {
  f32x4 z; z[0] = z[1] = z[2] = z[3] = 0.f; return z;
}
__device__ __forceinline__ void gload_lds16(const void* g, void* l) {
  __builtin_amdgcn_global_load_lds(
      (const __attribute__((address_space(1))) void*)g,
      (__attribute__((address_space(3))) void*)l, 16, 0, 0);
}

// ---------------- K0: weights -> bf16, [n][k] layout ----------------
__global__ __launch_bounds__(256) void k_prep(
    const float* __restrict__ Wq, const float* __restrict__ Wkv,
    const float* __restrict__ Wout,
    bf16* __restrict__ wall, bf16* __restrict__ woutt) {
  int t = blockIdx.x * 256 + threadIdx.x;   // grid covers 640*512
  int n = t >> 9, k = t & 511;
  float v = (n < DIM) ? Wq[k * DIM + n] : Wkv[k * 128 + (n - DIM)];
  wall[t] = (bf16)v;
  if (t < DIM * DIM) woutt[t] = (bf16)Wout[k * DIM + n];
}

// ---------------- kx_ln: LayerNorm(x)*g -> bf16 ----------------
__global__ __launch_bounds__(256) void kx_ln(
    const float* __restrict__ x, const float* __restrict__ gnorm,
    bf16* __restrict__ xn) {
  const int lane = threadIdx.x & 63;
  const int gw = blockIdx.x * 4 + (threadIdx.x >> 6);
  float gv[8];
  #pragma unroll
  for (int j = 0; j < 8; ++j) gv[j] = gnorm[lane * 8 + j];
  #pragma unroll
  for (int i = 0; i < 8; ++i) {
    size_t row = (size_t)gw * 8 + i;
    const float4* xp = (const float4*)(x + row * DIM + lane * 8);
    float4 v0 = xp[0], v1 = xp[1];
    float s  = v0.x + v0.y + v0.z + v0.w + v1.x + v1.y + v1.z + v1.w;
    float sq = v0.x*v0.x + v0.y*v0.y + v0.z*v0.z + v0.w*v0.w
             + v1.x*v1.x + v1.y*v1.y + v1.z*v1.z + v1.w*v1.w;
    #pragma unroll
    for (int d = 1; d < 64; d <<= 1) { s += __shfl_xor(s, d); sq += __shfl_xor(sq, d); }
    float mean = s * (1.f / 512.f);
    float var  = sq * (1.f / 512.f) - mean * mean;
    float rs   = rsqrtf(var + 1e-5f);
    bf16x8 o;
    o[0] = (bf16)((v0.x - mean) * rs * gv[0]);
    o[1] = (bf16)((v0.y - mean) * rs * gv[1]);
    o[2] = (bf16)((v0.z - mean) * rs * gv[2]);
    o[3] = (bf16)((v0.w - mean) * rs * gv[3]);
    o[4] = (bf16)((v1.x - mean) * rs * gv[4]);
    o[5] = (bf16)((v1.y - mean) * rs * gv[5]);
    o[6] = (bf16)((v1.z - mean) * rs * gv[6]);
    o[7] = (bf16)((v1.w - mean) * rs * gv[7]);
    *(bf16x8*)(xn + row * DIM + lane * 8) = o;
  }
}

// ---------------- m97-style GEMM: [M,640] = xn @ wall^T -> q,k,vT ----------
__global__ __launch_bounds__(256) void k_gemm_qkv(
    const bf16* __restrict__ xn, const bf16* __restrict__ wall,
    bf16* __restrict__ qbuf, bf16* __restrict__ kbuf, bf16* __restrict__ vtbuf) {
  __shared__ bf16 sa[2][128 * 32];
  __shared__ bf16 sb[2][128 * 32];
  const int t = threadIdx.x, wave = t >> 6, lane = t & 63;
  const int l15 = lane & 15, g = lane >> 4;
  const int wm = wave >> 1, wn = wave & 1;
  int wg = (blockIdx.x & 7) * 320 + (blockIdx.x >> 3);   // nwg=2560=8*320
  const int bm = wg / 5, bn = wg % 5;
  const char* Abase = (const char*)(xn   + (size_t)bm * 128 * DIM);
  const char* Bbase = (const char*)(wall + (size_t)bn * 128 * DIM);
  const int srow0 = wave * 16 + (lane >> 2);
  const int skb   = (lane & 3) * 16;

  #pragma unroll
  for (int c = 0; c < 2; ++c) {
    int row = c * 64 + srow0;
    int kb = skb ^ ((row & 3) << 4);
    gload_lds16(Abase + (size_t)row * 1024 + kb, (char*)&sa[0][0] + c * 4096 + wave * 1024);
    gload_lds16(Bbase + (size_t)row * 1024 + kb, (char*)&sb[0][0] + c * 4096 + wave * 1024);
  }
  __syncthreads();

  f32x4 acc[4][4];
  #pragma unroll
  for (int mi = 0; mi < 4; ++mi)
    #pragma unroll
    for (int ni = 0; ni < 4; ++ni) acc[mi][ni] = fzero4();

  #pragma unroll 2
  for (int step = 0; step < 16; ++step) {
    const int cur = step & 1;
    if (step < 15) {
      int kk2 = (step + 1) * 64;
      #pragma unroll
      for (int c = 0; c < 2; ++c) {
        int row = c * 64 + srow0;
        int kb = skb ^ ((row & 3) << 4);
        gload_lds16(Abase + (size_t)row * 1024 + kk2 + kb,
                    (char*)&sa[cur ^ 1][0] + c * 4096 + wave * 1024);
        gload_lds16(Bbase + (size_t)row * 1024 + kk2 + kb,
                    (char*)&sb[cur ^ 1][0] + c * 4096 + wave * 1024);
      }
    }
    bf16x8 a[4], b[4];
    #pragma unroll
    for (int mi = 0; mi < 4; ++mi) {
      int row = wm * 64 + mi * 16 + l15;
      a[mi] = *(const bf16x8*)((const char*)&sa[cur][0] + row * 64 + ((g * 16) ^ ((row & 3) << 4)));
    }
    #pragma unroll
    for (int ni = 0; ni < 4; ++ni) {
      int row = wn * 64 + ni * 16 + l15;
      b[ni] = *(const bf16x8*)((const char*)&sb[cur][0] + row * 64 + ((g * 16) ^ ((row & 3) << 4)));
    }
    #pragma unroll
    for (int mi = 0; mi < 4; ++mi)
      #pragma unroll
      for (int ni = 0; ni < 4; ++ni)
        acc[mi][ni] = mfma16(a[mi], b[ni], acc[mi][ni]);
    __syncthreads();
  }

  // epilogue: route cols to q / k / vT
  #pragma unroll
  for (int ni = 0; ni < 4; ++ni) {
    int col0 = bn * 128 + wn * 64 + ni * 16;
    if (col0 < 512) {
      bf16* dst = qbuf + col0 + l15;
      #pragma unroll
      for (int mi = 0; mi < 4; ++mi)
        #pragma unroll
        for (int jj = 0; jj < 4; ++jj) {
          size_t row = (size_t)bm * 128 + wm * 64 + mi * 16 + g * 4 + jj;
          dst[row * DIM] = (bf16)acc[mi][ni][jj];
        }
    } else if (col0 < 576) {
      bf16* dst = kbuf + (col0 - 512) + l15;
      #pragma unroll
      for (int mi = 0; mi < 4; ++mi)
        #pragma unroll
        for (int jj = 0; jj < 4; ++jj) {
          size_t row = (size_t)bm * 128 + wm * 64 + mi * 16 + g * 4 + jj;
          dst[row * DHEAD] = (bf16)acc[mi][ni][jj];
        }
    } else {
      // vT[bn_r][d][kv]: jj is kv-contiguous -> packed b64 store
      int d = col0 - 576 + l15;
      #pragma unroll
      for (int mi = 0; mi < 4; ++mi) {
        size_t row = (size_t)bm * 128 + wm * 64 + mi * 16 + g * 4;
        int bnr = (int)(row >> 8), kv = (int)(row & 255);
        bf16x4 v4;
        v4[0] = (bf16)acc[mi][ni][0]; v4[1] = (bf16)acc[mi][ni][1];
        v4[2] = (bf16)acc[mi][ni][2]; v4[3] = (bf16)acc[mi][ni][3];
        *(bf16x4*)(vtbuf + (size_t)bnr * 16384 + (size_t)d * 256 + kv) = v4;
      }
    }
  }
}

// ---------------- m97-style GEMM: obuf[M,512] = abuf @ woutt^T ----------------
__global__ __launch_bounds__(256) void k_gemm_out(
    const bf16* __restrict__ abuf, const bf16* __restrict__ woutt,
    bf16* __restrict__ obuf) {
  __shared__ bf16 sa[2][128 * 32];
  __shared__ bf16 sb[2][128 * 32];
  const int t = threadIdx.x, wave = t >> 6, lane = t & 63;
  const int l15 = lane & 15, g = lane >> 4;
  const int wm = wave >> 1, wn = wave & 1;
  int wg = (blockIdx.x & 7) * 256 + (blockIdx.x >> 3);   // nwg=2048=8*256
  const int bm = wg >> 2, bn = wg & 3;
  const char* Abase = (const char*)(abuf  + (size_t)bm * 128 * DIM);
  const char* Bbase = (const char*)(woutt + (size_t)bn * 128 * DIM);
  const int srow0 = wave * 16 + (lane >> 2);
  const int skb   = (lane & 3) * 16;

  #pragma unroll
  for (int c = 0; c < 2; ++c) {
    int row = c * 64 + srow0;
    int kb = skb ^ ((row & 3) << 4);
    gload_lds16(Abase + (size_t)row * 1024 + kb, (char*)&sa[0][0] + c * 4096 + wave * 1024);
    gload_lds16(Bbase + (size_t)row * 1024 + kb, (char*)&sb[0][0] + c * 4096 + wave * 1024);
  }
  __syncthreads();

  f32x4 acc[4][4];
  #pragma unroll
  for (int mi = 0; mi < 4; ++mi)
    #pragma unroll
    for (int ni = 0; ni < 4; ++ni) acc[mi][ni] = fzero4();

  #pragma unroll 2
  for (int step = 0; step < 16; ++step) {
    const int cur = step & 1;
    if (step < 15) {
      int kk2 = (step + 1) * 64;
      #pragma unroll
      for (int c = 0; c < 2; ++c) {
        int row = c * 64 + srow0;
        int kb = skb ^ ((row & 3) << 4);
        gload_lds16(Abase + (size_t)row * 1024 + kk2 + kb,
                    (char*)&sa[cur ^ 1][0] + c * 4096 + wave * 1024);
        gload_lds16(Bbase + (size_t)row * 1024 + kk2 + kb,
                    (char*)&sb[cur ^ 1][0] + c * 4096 + wave * 1024);
      }
    }
    bf16x8 a[4], b[4];
    #pragma unroll
    for (int mi = 0; mi < 4; ++mi) {
      int row = wm * 64 + mi * 16 + l15;
      a[mi] = *(const bf16x8*)((const char*)&sa[cur][0] + row * 64 + ((g * 16) ^ ((row & 3) << 4)));
    }
    #pragma unroll
    for (int ni = 0; ni < 4; ++ni) {
      int row = wn * 64 + ni * 16 + l15;
      b[ni] = *(const bf16x8*)((const char*)&sb[cur][0] + row * 64 + ((g * 16) ^ ((row & 3) << 4)));
    }
    #pragma unroll
    for (int mi = 0; mi < 4; ++mi)
      #pragma unroll
      for (int ni = 0; ni < 4; ++ni)
        acc[mi][ni] = mfma16(a[mi], b[ni], acc[mi][ni]);
    __syncthreads();
  }

  #pragma unroll
  for (int ni = 0; ni < 4; ++ni) {
    int col = bn * 128 + wn * 64 + ni * 16 + l15;
    #pragma unroll
    for (int mi = 0; mi < 4; ++mi)
      #pragma unroll
      for (int jj = 0; jj < 4; ++jj) {
        size_t row = (size_t)bm * 128 + wm * 64 + mi * 16 + g * 4 + jj;
        obuf[row * DIM + col] = (bf16)acc[mi][ni][jj];
      }
  }
}

// ---------------- k_ln_out: LayerNorm(obuf)*g_out -> f32 ----------------
__global__ __launch_bounds__(256) void k_ln_out(
    const bf16* __restrict__ obuf, const float* __restrict__ gout,
    float* __restrict__ out) {
  const int lane = threadIdx.x & 63;
  const int gw = blockIdx.x * 4 + (threadIdx.x >> 6);
  float gv[8];
  #pragma unroll
  for (int j = 0; j < 8; ++j) gv[j] = gout[lane * 8 + j];
  #pragma unroll
  for (int i = 0; i < 8; ++i) {
    size_t row = (size_t)gw * 8 + i;
    bf16x8 v = *(const bf16x8*)(obuf + row * DIM + lane * 8);
    float f[8];
    float s = 0.f, sq = 0.f;
    #pragma unroll
    for (int j = 0; j < 8; ++j) { f[j] = (float)v[j]; s += f[j]; sq += f[j] * f[j]; }
    #pragma unroll
    for (int d = 1; d < 64; d <<= 1) { s += __shfl_xor(s, d); sq += __shfl_xor(sq, d); }
    float mean = s * (1.f / 512.f);
    float var  = sq * (1.f / 512.f) - mean * mean;
    float rs   = rsqrtf(var + 1e-5f);
    float4 o0, o1;
    o0.x = (f[0]-mean)*rs*gv[0]; o0.y = (f[1]-mean)*rs*gv[1];
    o0.z = (f[2]-mean)*rs*gv[2]; o0.w = (f[3]-mean)*rs*gv[3];
    o1.x = (f[4]-mean)*rs*gv[4]; o1.y = (f[5]-mean)*rs*gv[5];
    o1.z = (f[6]-mean)*rs*gv[6]; o1.w = (f[7]-mean)*rs*gv[7];
    float4* op = (float4*)(out + row * DIM + lane * 8);
    op[0] = o0; op[1] = o1;
  }
}

// ---------------- k_attn: swapped QK^T, register-resident P ----------------
// 512 thr (8 waves x 32 q-rows). K[256][64] + V^T[64][256] staged once (64 KB,
// 2 blocks/CU). S^T = mfma(K,Q) puts a full P row (fixed q=l15+16qh) in-lane:
// kv = f*16 + 4g + jj == the A-fragment of v_mfma_f32_16x16x16_bf16. PV runs
// straight from registers; V^T read as bf16x4 B-fragments. One barrier total.
__global__ __launch_bounds__(512, 2) void k_attn(
    bf16* __restrict__ qbuf, const bf16* __restrict__ kbuf,
    const bf16* __restrict__ vtbuf) {
  __shared__ bf16 lk[256 * 64];     // 32 KB: [kv][d], 16B-unit swizzle u^=(row&7)
  __shared__ bf16 lvt[64 * 256];    // 32 KB: [d][kv], unit swizzle u^=(row&7)
  const int t = threadIdx.x, wave = t >> 6, lane = t & 63;
  const int l15 = lane & 15, g = lane >> 4;
  int wg = (blockIdx.x & 7) * 256 + (blockIdx.x >> 3);  // 8 heads/bn on one XCD
  const int bn = wg >> 3, h = wg & 7;
  const size_t tok0 = (size_t)bn * RLEN;
  const int m0 = wave * 32;

  // ---- stage K and V^T (async DMA; source pre-swizzled, LDS linear)
  {
    const char* ksrc = (const char*)(kbuf + tok0 * DHEAD);
    const char* vsrc = (const char*)(vtbuf + (size_t)bn * 64 * 256);
    #pragma unroll
    for (int i = 0; i < 4; ++i) {
      int d = i * 8192 + wave * 1024 + lane * 16;
      int krow = d >> 7, ku = (d >> 4) & 7;
      gload_lds16(ksrc + (krow << 7) + ((ku ^ (krow & 7)) << 4),
                  (char*)lk + i * 8192 + wave * 1024);
      int vrow = d >> 9, vu = (d >> 4) & 31;
      gload_lds16(vsrc + (vrow << 9) + ((vu ^ (vrow & 7)) << 4),
                  (char*)lvt + i * 8192 + wave * 1024);
    }
  }
  // Q fragments (B-operand of swapped QK^T): Q[q = l15+16qh][d = g*8+j (+32ks)]
  bf16x8 aq[2][2];
  {
    const bf16* qb = qbuf + (tok0 + m0 + l15) * DIM + h * DHEAD + g * 8;
    #pragma unroll
    for (int qh = 0; qh < 2; ++qh)
      #pragma unroll
      for (int ks = 0; ks < 2; ++ks)
        aq[qh][ks] = *(const bf16x8*)(qb + (size_t)qh * 16 * DIM + ks * 32);
  }
  __syncthreads();   // single barrier: K/V^T in LDS

  const float C = 0.1803368801f;   // 0.125 * log2(e)
  bf16x4 pa[2][16];                // register-resident P (A-frags, K=16)
  float linv[2];

  #pragma unroll
  for (int qh = 0; qh < 2; ++qh) {
    // ---- S^T = K Q^T : s2[f][jj] = S[q = l15+16qh][kv = f*16 + 4g + jj]
    f32x4 s2[16];
    #pragma unroll
    for (int f = 0; f < 16; ++f) s2[f] = fzero4();
    #pragma unroll
    for (int f = 0; f < 16; ++f) {
      int row = l15 + 16 * f;
      const char* lkb = (const char*)lk + (row << 7);
      int sw = (row & 7) << 4;
      bf16x8 bk0 = *(const bf16x8*)(lkb + ((g << 4) ^ sw));
      bf16x8 bk1 = *(const bf16x8*)(lkb + (((4 + g) << 4) ^ sw));
      s2[f] = mfma16(bk0, aq[qh][0], s2[f]);
      s2[f] = mfma16(bk1, aq[qh][1], s2[f]);
    }
    // ---- row max: 63 in-lane fmax + 2 shfl (full 256 kv)
    float m = s2[0][0];
    #pragma unroll
    for (int f = 0; f < 16; ++f)
      #pragma unroll
      for (int jj = 0; jj < 4; ++jj)
        if (f | jj) m = fmaxf(m, s2[f][jj]);
    m = fmaxf(m, __shfl_xor(m, 16));
    m = fmaxf(m, __shfl_xor(m, 32));
    // ---- exp in place -> bf16 A-frags; in-lane sum
    float nmc = -m * C;
    float lsum = 0.f;
    #pragma unroll
    for (int f = 0; f < 16; ++f) {
      float p0 = exp2f(__builtin_fmaf(s2[f][0], C, nmc));
      float p1 = exp2f(__builtin_fmaf(s2[f][1], C, nmc));
      float p2 = exp2f(__builtin_fmaf(s2[f][2], C, nmc));
      float p3 = exp2f(__builtin_fmaf(s2[f][3], C, nmc));
      lsum += (p0 + p1) + (p2 + p3);
      bf16x4 pk;
      pk[0] = (bf16)p0; pk[1] = (bf16)p1; pk[2] = (bf16)p2; pk[3] = (bf16)p3;
      pa[qh][f] = pk;
    }
    lsum += __shfl_xor(lsum, 16);
    lsum += __shfl_xor(lsum, 32);
    linv[qh] = 1.0f / lsum;        // valid for q = l15 + 16*qh
  }

  // ---- PV from registers: K=16 steps over kv; V^T b64 B-frags
  f32x4 o2[2][4];
  #pragma unroll
  for (int qh = 0; qh < 2; ++qh)
    #pragma unroll
    for (int di = 0; di < 4; ++di) o2[qh][di] = fzero4();
  #pragma unroll
  for (int f = 0; f < 16; ++f) {
    #pragma unroll
    for (int di = 0; di < 4; ++di) {
      int row = l15 + 16 * di;
      int unit = (2 * f + (g >> 1)) ^ (row & 7);
      bf16x4 bv = *(const bf16x4*)((const char*)lvt + (row << 9) + (unit << 4) + ((g & 1) << 3));
      o2[0][di] = mfma_k16(pa[0][f], bv, o2[0][di]);
      o2[1][di] = mfma_k16(pa[1][f], bv, o2[1][di]);
    }
  }

  // ---- normalize (broadcast 1/lsum from lane q=4g+jj) and write back
  #pragma unroll
  for (int qh = 0; qh < 2; ++qh)
    #pragma unroll
    for (int jj = 0; jj < 4; ++jj) {
      float inv = __shfl(linv[qh], 4 * g + jj);
      size_t row = tok0 + m0 + qh * 16 + 4 * g + jj;
      #pragma unroll
      for (int di = 0; di < 4; ++di)
        qbuf[row * DIM + h * DHEAD + di * 16 + l15] = (bf16)(o2[qh][di][jj] * inv);
    }
}

// ---------------- launch ----------------
extern "C" void kernel_launch(void* const* d_in, const int* in_sizes, int n_in,
                              void* d_out, int out_size, void* d_ws, size_t ws_size,
                              hipStream_t stream) {
  const float* x     = (const float*)d_in[0];
  const float* gnorm = (const float*)d_in[1];
  const float* Wq    = (const float*)d_in[2];
  const float* Wkv   = (const float*)d_in[3];
  const float* Wout  = (const float*)d_in[4];
  const float* gout  = (const float*)d_in[5];
  float* out = (float*)d_out;
  char* ws = (char*)d_ws;
  // ws: wall 640K | woutt 512K | xnbuf/obuf 64M (aliased) | qbuf 64M | kbuf 8M | vtbuf 8M
  bf16* wall  = (bf16*)(ws);
  bf16* woutt = (bf16*)(ws + 655360);
  bf16* xnbuf = (bf16*)(ws + 1179648);
  bf16* obuf  = xnbuf;   // xn dead after k_gemm_qkv
  bf16* qbuf  = (bf16*)(ws + 1179648 + (size_t)TOK * DIM * 2);
  bf16* kbuf  = (bf16*)((char*)qbuf + (size_t)TOK * DIM * 2);
  bf16* vtbuf = (bf16*)((char*)kbuf + (size_t)TOK * DHEAD * 2);

  k_prep    <<<dim3(1280), dim3(256), 0, stream>>>(Wq, Wkv, Wout, wall, woutt);
  kx_ln     <<<dim3(2048), dim3(256), 0, stream>>>(x, gnorm, xnbuf);
  k_gemm_qkv<<<dim3(2560), dim3(256), 0, stream>>>(xnbuf, wall, qbuf, kbuf, vtbuf);
  k_attn    <<<dim3(2048), dim3(512), 0, stream>>>(qbuf, kbuf, vtbuf);
  k_gemm_out<<<dim3(2048), dim3(256), 0, stream>>>(qbuf, woutt, obuf);
  k_ln_out  <<<dim3(2048), dim3(256), 0, stream>>>(obuf, gout, out);
}